// Round 1
// baseline (86.508 us; speedup 1.0000x reference)
//
#include <hip/hip_runtime.h>

#define CCH 128
#define SPW 64
#define SPH 64
#define SP  (SPW*SPH)   // 4096 spatial positions per (b,c)

__device__ __forceinline__ float sigmoidf_(float z) {
  return 1.0f / (1.0f + __expf(-z));
}

// y[brel, o, n] = sum_c attn_w[o][c] * x[b0+brel, c, n]   (1x1 conv over channels)
// grid: nb*64 blocks, 256 threads. Each block: one b, 64 spatial columns.
// Each thread: one column n, 32 output channels.
__global__ __launch_bounds__(256) void k_conv1x1(
    const float* __restrict__ x, const float* __restrict__ attn_w,
    float* __restrict__ y, int b0) {
  // transposed weights in LDS: w_t[c][o], padded stride 132 (float4-aligned,
  // breaks the worst transpose-write bank pattern; main-loop reads are
  // wave-uniform broadcasts so conflict-free regardless)
  __shared__ float w_t[CCH * 132];
  for (int idx = threadIdx.x; idx < CCH * CCH; idx += 256) {
    int o = idx >> 7, c = idx & (CCH - 1);
    w_t[c * 132 + o] = attn_w[idx];
  }
  __syncthreads();

  int blk  = blockIdx.x;
  int brel = blk >> 6;
  int b    = b0 + brel;
  int n    = ((blk & 63) << 6) + (threadIdx.x & 63);
  int og   = (threadIdx.x >> 6) << 5;  // 0,32,64,96: o-range per wave

  const float* xb = x + (size_t)b * CCH * SP + n;
  float acc[32];
#pragma unroll
  for (int i = 0; i < 32; i++) acc[i] = 0.0f;

#pragma unroll 4
  for (int c = 0; c < CCH; c++) {
    float xv = xb[(size_t)c * SP];                       // coalesced 256B/wave, L1-reused x4
    const float4* wr = (const float4*)&w_t[c * 132 + og]; // wave-uniform broadcast
#pragma unroll
    for (int j = 0; j < 8; j++) {
      float4 wv = wr[j];
      acc[4*j+0] = fmaf(xv, wv.x, acc[4*j+0]);
      acc[4*j+1] = fmaf(xv, wv.y, acc[4*j+1]);
      acc[4*j+2] = fmaf(xv, wv.z, acc[4*j+2]);
      acc[4*j+3] = fmaf(xv, wv.w, acc[4*j+3]);
    }
  }

  float* yb = y + (size_t)brel * CCH * SP + n;
#pragma unroll
  for (int j = 0; j < 32; j++) yb[(size_t)(og + j) * SP] = acc[j];  // coalesced
}

// out[b,c,w,h] = max_s se[s]*xg * sigmoid(se[s]*yg + attn_b[c]) over the 9
// flat-view gathered positions; OOB gather -> weighted=0 -> candidate 0.
__global__ __launch_bounds__(256) void k_attnmax(
    const float* __restrict__ x, const float* __restrict__ y,
    const float* __restrict__ se_param, const float* __restrict__ attn_b,
    float* __restrict__ out, int b0) {
  __shared__ float se9[9];
  if (threadIdx.x < 9) se9[threadIdx.x] = sigmoidf_(se_param[threadIdx.x]);
  __syncthreads();

  int idx  = blockIdx.x * 256 + threadIdx.x;  // over nb * C * SP
  int brel = idx >> 19;                        // C*SP = 524288 = 2^19
  int c    = (idx >> 12) & (CCH - 1);
  int wh   = idx & (SP - 1);
  int b    = b0 + brel;

  const float* xb = x + ((size_t)b * CCH + c) * SP;
  const float* yb = y + ((size_t)brel * CCH + c) * SP;
  float ab = attn_b[c];

  float m = -3.4e38f;
#pragma unroll
  for (int s = 0; s < 9; s++) {
    int q  = s * SP + wh;          // flat index into the reinterpreted view
    int wi = q / 576;              // magic-mul division by constant
    int r  = q - wi * 576;
    int hi = r / 9;
    int k  = r - hi * 9;
    int di = k / 3;
    int dj = k - di * 3;
    int sw = wi + di - 1;
    int sh = hi + dj - 1;
    float v = 0.0f;
    if ((unsigned)sw < 64u && (unsigned)sh < 64u) {
      int off  = (sw << 6) + sh;
      float se = se9[s];
      float xx = xb[off];
      float yy = yb[off];
      v = se * xx * sigmoidf_(fmaf(se, yy, ab));
    }
    m = fmaxf(m, v);
  }
  out[((size_t)b * CCH + c) * SP + wh] = m;
}

extern "C" void kernel_launch(void* const* d_in, const int* in_sizes, int n_in,
                              void* d_out, int out_size, void* d_ws, size_t ws_size,
                              hipStream_t stream) {
  const float* x        = (const float*)d_in[0];
  const float* se_param = (const float*)d_in[1];
  const float* attn_w   = (const float*)d_in[2];
  const float* attn_b   = (const float*)d_in[3];
  float* out = (float*)d_out;
  float* y   = (float*)d_ws;

  int B = in_sizes[0] / (CCH * SP);            // 8
  size_t per_b = (size_t)CCH * SP * sizeof(float);  // 2 MB of y per batch
  int chunk = (ws_size >= per_b) ? (int)(ws_size / per_b) : 1;
  if (chunk > B) chunk = B;

  for (int b0 = 0; b0 < B; b0 += chunk) {
    int nb = (B - b0 < chunk) ? (B - b0) : chunk;
    k_conv1x1<<<dim3(nb * 64), dim3(256), 0, stream>>>(x, attn_w, y, b0);
    k_attnmax<<<dim3(nb * CCH * SP / 256), dim3(256), 0, stream>>>(
        x, y, se_param, attn_b, out, b0);
  }
}

// Round 2
// 72.280 us; speedup vs baseline: 1.1968x; 1.1968x over previous
//
#include <hip/hip_runtime.h>

#define CCH 128
#define SP  4096          // 64*64 spatial positions per (b,c)
#define LSTR 72           // padded LDS row stride (floats): bank=(8*sw+sh)%32 spreads taps
#define TBL_N (9 * SP)    // table entries

__device__ __forceinline__ float sigmoidf_(float z) {
  return 1.0f / (1.0f + __expf(-z));
}

// One-time gather table: tbl[s*4096+wh] = LDS offset (sw*72+sh) or 0xFFFF if OOB.
// Depends only on wh, reused across all 1024 (b,c) planes.
__global__ __launch_bounds__(256) void k_table(unsigned short* __restrict__ tbl) {
  int i = blockIdx.x * 256 + threadIdx.x;
  if (i >= TBL_N) return;
  int s  = i >> 12, wh = i & (SP - 1);
  int q  = (s << 12) + wh;       // flat index into torch's reinterpreted view
  int wi = q / 576;  int r  = q - wi * 576;
  int hi = r / 9;    int kk = r - hi * 9;
  int di = kk / 3,   dj = kk - di * 3;
  int sw = wi + di - 1, sh = hi + dj - 1;
  tbl[i] = (((unsigned)sw < 64u) & ((unsigned)sh < 64u))
               ? (unsigned short)(sw * LSTR + sh) : (unsigned short)0xFFFFu;
}

// y[b,o,n] = sum_c attn_w[o][c] * x[b,c,n], written into d_out.
// Block: 512 threads = 8 waves; wave = 64 spatial columns x 16 output channels.
// Weight reads are wave-uniform (readfirstlane o0) -> scalar/K$ path, no LDS.
__global__ __launch_bounds__(512) void k_conv1x1(
    const float* __restrict__ x, const float* __restrict__ attn_w,
    float* __restrict__ y) {
  int b  = blockIdx.x >> 6;
  int n  = ((blockIdx.x & 63) << 6) | (threadIdx.x & 63);
  int o0 = __builtin_amdgcn_readfirstlane((threadIdx.x >> 6) << 4);  // 0,16,...,112

  const float* xb = x + ((size_t)b << 19) + n;     // b*128*4096
  const float* wb = attn_w + ((size_t)o0 << 7);    // attn_w[o][c] row-major

  float acc[16];
#pragma unroll
  for (int j = 0; j < 16; j++) acc[j] = 0.0f;

#pragma unroll 4
  for (int cc = 0; cc < CCH; cc++) {
    float xv = xb[(size_t)cc << 12];               // coalesced 256B/wave, L1-reused x8
#pragma unroll
    for (int j = 0; j < 16; j++)
      acc[j] = fmaf(xv, wb[(j << 7) + cc], acc[j]); // wave-uniform -> s_load/L1 broadcast
  }

  float* yb = y + ((size_t)b << 19) + n;
#pragma unroll
  for (int j = 0; j < 16; j++) yb[(size_t)(o0 + j) << 12] = acc[j];  // coalesced
}

// out[b,c,wh] = max_s se[s]*xg * sigmoid(se[s]*yg + attn_b[c]).
// Block = one (b,c) plane. Stage x-plane + y-plane (y read from d_out) into
// padded LDS, sync, gather from LDS, overwrite the same d_out plane.
template <bool TBL>
__global__ __launch_bounds__(256) void k_attnmax(
    const float* __restrict__ x, float* __restrict__ yo,
    const float* __restrict__ se_param, const float* __restrict__ attn_b,
    const unsigned short* __restrict__ tbl) {
  __shared__ float lx[64 * LSTR];
  __shared__ float ly[64 * LSTR];
  __shared__ float se9[12];

  int bc = blockIdx.x;            // b*128 + c
  int c  = bc & (CCH - 1);
  const float* xp = x  + ((size_t)bc << 12);
  float*       yp = yo + ((size_t)bc << 12);

  if (threadIdx.x < 9) se9[threadIdx.x] = sigmoidf_(se_param[threadIdx.x]);

  for (int i = threadIdx.x; i < SP / 4; i += 256) {   // 1024 float4 per plane
    float4 vx = ((const float4*)xp)[i];
    float4 vy = ((const float4*)yp)[i];
    int a = (i >> 4) * LSTR + ((i & 15) << 2);        // row=i/16, col=(i%16)*4
    *(float4*)&lx[a] = vx;
    *(float4*)&ly[a] = vy;
  }
  float ab = attn_b[c];
  __syncthreads();

  for (int k = 0; k < 16; k++) {
    int wh = (k << 8) | threadIdx.x;
    float m = -3.4e38f;
#pragma unroll
    for (int s = 0; s < 9; s++) {
      int off; bool valid;
      if (TBL) {
        unsigned short t = tbl[(s << 12) | wh];       // coalesced, L1/L2-hot
        valid = (t != 0xFFFFu);
        off = valid ? (int)t : 0;
      } else {
        int q  = (s << 12) + wh;
        int wi = q / 576;  int r  = q - wi * 576;
        int hi = r / 9;    int kk = r - hi * 9;
        int di = kk / 3,   dj = kk - di * 3;
        int sw = wi + di - 1, sh = hi + dj - 1;
        valid = ((unsigned)sw < 64u) & ((unsigned)sh < 64u);
        off = valid ? sw * LSTR + sh : 0;
      }
      float se = se9[s];
      float xx = lx[off], yy = ly[off];
      float v  = se * xx * sigmoidf_(fmaf(se, yy, ab));
      v = valid ? v : 0.0f;      // OOB tap contributes weighted=0
      m = fmaxf(m, v);
    }
    yp[wh] = m;                  // overwrite y-plane with result (y is in LDS)
  }
}

extern "C" void kernel_launch(void* const* d_in, const int* in_sizes, int n_in,
                              void* d_out, int out_size, void* d_ws, size_t ws_size,
                              hipStream_t stream) {
  const float* x        = (const float*)d_in[0];
  const float* se_param = (const float*)d_in[1];
  const float* attn_w   = (const float*)d_in[2];
  const float* attn_b   = (const float*)d_in[3];
  float* out = (float*)d_out;

  int B = in_sizes[0] / (CCH * SP);
  unsigned short* tbl = (unsigned short*)d_ws;
  bool use_tbl = ws_size >= (size_t)TBL_N * sizeof(unsigned short);

  if (use_tbl)
    k_table<<<dim3((TBL_N + 255) / 256), dim3(256), 0, stream>>>(tbl);

  k_conv1x1<<<dim3(B * 64), dim3(512), 0, stream>>>(x, attn_w, out);

  if (use_tbl)
    k_attnmax<true><<<dim3(B * CCH), dim3(256), 0, stream>>>(
        x, out, se_param, attn_b, tbl);
  else
    k_attnmax<false><<<dim3(B * CCH), dim3(256), 0, stream>>>(
        x, out, se_param, attn_b, nullptr);
}